// Round 22
// baseline (138.936 us; speedup 1.0000x reference)
//
#include <hip/hip_runtime.h>
#include <hip/hip_fp16.h>

#define HD 8
#define CD 16
#define DIM 128
#define NEG_SLOPE 0.2f
#define RSHIFT 13
#define RSIZE (1<<RSHIFT)                   // 8192-node range per histogram block (32KB LDS)
#define SEG 32                              // edge segments

typedef __attribute__((ext_vector_type(8))) _Float16 f16x8;
typedef __attribute__((ext_vector_type(4))) float    f32x4;

static __device__ __forceinline__ float lrelu(float v){ return v > 0.f ? v : NEG_SLOPE*v; }

// ---------------- K0: W fp32 [k][c] -> Wt fp16 [c][k] ----------------
__global__ __launch_bounds__(256) void k_wprep(const float* __restrict__ W, __half* __restrict__ Wt){
  int idx = blockIdx.x*256 + threadIdx.x;
  if (idx < DIM*DIM){
    int k = idx >> 7, c = idx & 127;
    Wt[(size_t)c*DIM + k] = __float2half(W[idx]);
  }
}

// ---------------- K1: h = x @ W via MFMA fp16, + alpha epilogue (r10-verified) -------------
__global__ __launch_bounds__(256, 3) void k_gemm(const float* __restrict__ x,
    const __half* __restrict__ Wt, const float* __restrict__ a_src_g, const float* __restrict__ a_dst_g,
    __half* __restrict__ hout, float* __restrict__ as_o, float* __restrict__ ad_o, int N)
{
  __shared__ __half xs[64*136];
  const int tid  = threadIdx.x;
  const int lane = tid & 63;
  const int wv   = tid >> 6;
  const long nbase = (long)blockIdx.x * 64;

  #pragma unroll
  for (int it = 0; it < 8; ++it){
    int lin = it*1024 + tid*4;
    int row = lin >> 7, col = lin & 127;
    long node = nbase + row;
    float4 v = make_float4(0.f,0.f,0.f,0.f);
    if (node < N) v = *(const float4*)(x + node*DIM + col);
    __half2* dstp = (__half2*)(xs + row*136 + col);
    dstp[0] = __floats2half2_rn(v.x, v.y);
    dstp[1] = __floats2half2_rn(v.z, v.w);
  }
  __syncthreads();

  const int lrow = lane & 15;
  const int g    = lane >> 4;

  f16x8 af[4];
  #pragma unroll
  for (int ks = 0; ks < 4; ++ks)
    af[ks] = *(const f16x8*)(xs + (wv*16 + lrow)*136 + ks*32 + g*8);

  f32x4 accs[8];
  #pragma unroll
  for (int t = 0; t < 8; ++t){
    f32x4 acc = {0.f,0.f,0.f,0.f};
    #pragma unroll
    for (int ks = 0; ks < 4; ++ks){
      f16x8 bf = *(const f16x8*)(Wt + (size_t)(t*16 + lrow)*DIM + ks*32 + g*8);
      acc = __builtin_amdgcn_mfma_f32_16x16x32_f16(af[ks], bf, acc, 0, 0, 0);
    }
    accs[t] = acc;
  }

  #pragma unroll
  for (int t = 0; t < 8; ++t)
    #pragma unroll
    for (int i = 0; i < 4; ++i)
      xs[(wv*16 + g*4 + i)*136 + t*16 + lrow] = __float2half(accs[t][i]);
  __syncthreads();

  #pragma unroll
  for (int j = 0; j < 4; ++j){
    int idx = j*256 + tid;
    int row = idx >> 4, seg = idx & 15;
    long node = nbase + row;
    if (node < N){
      uint4 v = *(const uint4*)((const char*)xs + row*272 + seg*16);
      *(uint4*)(hout + node*DIM + seg*8) = v;
    }
  }
  #pragma unroll
  for (int j = 0; j < 2; ++j){
    int idx = j*256 + tid;
    int row = idx >> 3, hd = idx & 7;
    long node = nbase + row;
    if (node < N){
      const __half* hp = xs + row*136 + hd*16;
      float ps = 0.f, pd = 0.f;
      #pragma unroll
      for (int cc = 0; cc < 16; ++cc){
        float hv = __half2float(hp[cc]);
        ps += hv * a_src_g[hd*16 + cc];
        pd += hv * a_dst_g[hd*16 + cc];
      }
      as_o[node*HD + hd] = ps;
      ad_o[node*HD + hd] = pd;
    }
  }
}

// ---------------- K2: LDS-histogram count (NO global atomics) ----------------
// Block (range p, segment s): 32KB LDS histogram over p's 8192 nodes; stream segment s's
// dsts; LDS-atomic for in-range (1-in-7). Histogram plane written coalescedly — cnt_seg
// needs no pre-zeroing. Replaces 600K global atomics (r18/r21: per-op cost, scope/address
// independent) with 600K LDS atomics + 16.8MB of streaming reads.
__global__ __launch_bounds__(256) void k_count(const int* __restrict__ dst,
                                               int* __restrict__ cnt_seg, int E, int N, int Eseg){
  __shared__ int hist[RSIZE];
  const int p = blockIdx.x / SEG;
  const int s = blockIdx.x % SEG;
  for (int i = threadIdx.x; i < RSIZE; i += 256) hist[i] = 0;
  __syncthreads();
  const int lo = p << RSHIFT;
  const int end = min((s+1)*Eseg, E);
  for (int e = s*Eseg + threadIdx.x; e < end; e += 256){
    unsigned r = (unsigned)(dst[e] - lo);
    if (r < RSIZE) atomicAdd(&hist[r], 1);
  }
  __syncthreads();
  for (int i = threadIdx.x; i < RSIZE; i += 256){
    int node = lo + i;
    if (node < N) cnt_seg[(size_t)s*N + node] = hist[i];
  }
}

// ---------------- CSR scans over SEG planes ----------------
__global__ __launch_bounds__(256) void k_scan1(const int* __restrict__ cnt_seg, int* __restrict__ bsum,
                                               int chunk, int N){
  __shared__ int tmp[256];
  int t = threadIdx.x;
  int i = blockIdx.x*chunk + t;
  int v = 0;
  if (t < chunk && i < N){
    #pragma unroll
    for (int s = 0; s < SEG; ++s) v += cnt_seg[(size_t)s*N + i];
  }
  tmp[t] = v; __syncthreads();
  for (int off = 128; off > 0; off >>= 1){
    if (t < off) tmp[t] += tmp[t+off];
    __syncthreads();
  }
  if (t == 0) bsum[blockIdx.x] = tmp[0];
}

__global__ __launch_bounds__(256) void k_scan2(int* __restrict__ bsum, int* __restrict__ row_ofs, int N){
  __shared__ int tmp[256];
  int t = threadIdx.x;
  int v = bsum[t];
  tmp[t] = v; __syncthreads();
  for (int off = 1; off < 256; off <<= 1){
    int u = (t >= off) ? tmp[t-off] : 0;
    __syncthreads();
    tmp[t] += u;
    __syncthreads();
  }
  bsum[t] = tmp[t] - v;            // exclusive
  if (t == 255) row_ofs[N] = tmp[255];
}

// scan3: row_ofs + s-major per-segment offsets cofs[s*N+d]
__global__ __launch_bounds__(256) void k_scan3(const int* __restrict__ cnt_seg, const int* __restrict__ bsum,
                                               int* __restrict__ row_ofs, int* __restrict__ cofs,
                                               int chunk, int N){
  __shared__ int tmp[256];
  int t = threadIdx.x;
  int i = blockIdx.x*chunk + t;
  int v[SEG]; int tot = 0;
  if (t < chunk && i < N){
    #pragma unroll
    for (int s = 0; s < SEG; ++s){ v[s] = cnt_seg[(size_t)s*N + i]; tot += v[s]; }
  }
  tmp[t] = tot; __syncthreads();
  for (int off = 1; off < 256; off <<= 1){
    int u = (t >= off) ? tmp[t-off] : 0;
    __syncthreads();
    tmp[t] += u;
    __syncthreads();
  }
  int excl = tmp[t] - tot;
  int bbase = bsum[blockIdx.x];
  if (t < chunk && i < N){
    int run = bbase + excl;
    row_ofs[i] = run;
    #pragma unroll
    for (int s = 0; s < SEG; ++s){ cofs[(size_t)s*N + i] = run; run += v[s]; }
  }
}

// ---------------- K3: LDS-histogram scatter (NO atomics, no slot array) ----------------
// Same (p,s) blocking; recomputes within-(d,s) slots via its own LDS histogram — any
// within-row permutation is valid (aggregation is order-independent), so count/scatter
// slot orders need not match. Writes land in range p's csr slice (r16-style L2 locality).
__global__ __launch_bounds__(256) void k_scatter(const int* __restrict__ src, const int* __restrict__ dst,
                                                 const int* __restrict__ cofs, int* __restrict__ csr_src,
                                                 int E, int N, int Eseg){
  __shared__ int hist[RSIZE];
  const int p = blockIdx.x / SEG;
  const int s = blockIdx.x % SEG;
  for (int i = threadIdx.x; i < RSIZE; i += 256) hist[i] = 0;
  __syncthreads();
  const int lo = p << RSHIFT;
  const int end = min((s+1)*Eseg, E);
  for (int e = s*Eseg + threadIdx.x; e < end; e += 256){
    int d = dst[e];
    unsigned r = (unsigned)(d - lo);
    if (r < RSIZE){
      int ls = atomicAdd(&hist[r], 1);
      csr_src[cofs[(size_t)s*N + d] + ls] = src[e];
    }
  }
}

// ---------------- K4: weighted gather (fp16 h), COOPERATIVE weights ----------------
__global__ __launch_bounds__(256) void k_aggr(const __half* __restrict__ h,
    const float* __restrict__ as_, const float* __restrict__ ad_,
    const int* __restrict__ row_ofs, const int* __restrict__ csr_src,
    const float* __restrict__ bias, float* __restrict__ out, int N)
{
  const int n = blockIdx.x*4 + (threadIdx.x >> 6);
  if (n >= N) return;
  const int t  = threadIdx.x & 63;
  const int hb = t >> 3;
  const int sl = t & 7;
  const int off = t*2;

  const float ad_n = ad_[(size_t)n*HD + hb];
  const float w_self = __expf(lrelu(as_[(size_t)n*HD + hb] + ad_n));

  float sum = w_self;
  float2 hv = __half22float2(*(const __half2*)(h + (size_t)n*DIM + off));
  float2 acc; acc.x = w_self*hv.x; acc.y = w_self*hv.y;

  const int ofs = row_ofs[n];
  const int deg = row_ofs[n+1] - ofs;

  for (int jb = 0; jb < deg; jb += 16){
    const int c = deg - jb;               // valid slots this chunk (>=1)
    int s[16];
    #pragma unroll
    for (int q = 0; q < 16; ++q){
      int sq = csr_src[ofs + jb + q];     // padded: safe to over-read
      s[q] = (q < c) ? sq : n;
    }

    __half2 hq[16];                        // 16 independent gathers, 1 VGPR each
    #pragma unroll
    for (int q = 0; q < 16; ++q)
      hq[q] = *(const __half2*)(h + (size_t)s[q]*DIM + off);

    float v0 = __expf(lrelu(as_[(size_t)s[sl]*HD + hb] + ad_n));
    float v1 = __expf(lrelu(as_[(size_t)s[sl+8]*HD + hb] + ad_n));
    const float wv0 = (sl     < c) ? v0 : 0.f;
    const float wv1 = (sl + 8 < c) ? v1 : 0.f;

    #pragma unroll
    for (int q = 0; q < 8; ++q){
      float w0 = __shfl(wv0, hb*8 + q);
      float2 hf = __half22float2(hq[q]);
      sum += w0; acc.x += w0*hf.x; acc.y += w0*hf.y;
    }
    #pragma unroll
    for (int q = 0; q < 8; ++q){
      float w1 = __shfl(wv1, hb*8 + q);
      float2 hf = __half22float2(hq[8+q]);
      sum += w1; acc.x += w1*hf.x; acc.y += w1*hf.y;
    }
  }

  const float2 bv = *(const float2*)(bias + off);
  const float inv = 1.0f / (sum + 1e-16f);
  float2 o;
  o.x = acc.x*inv + bv.x;
  o.y = acc.y*inv + bv.y;
  *(float2*)(out + (size_t)n*DIM + off) = o;
}

extern "C" void kernel_launch(void* const* d_in, const int* in_sizes, int n_in,
                              void* d_out, int out_size, void* d_ws, size_t ws_size,
                              hipStream_t stream)
{
  const float* x     = (const float*)d_in[0];
  const int*   ei    = (const int*)  d_in[1];
  const float* W     = (const float*)d_in[2];
  const float* a_src = (const float*)d_in[3];
  const float* a_dst = (const float*)d_in[4];
  const float* bias  = (const float*)d_in[5];
  float* out = (float*)d_out;

  const int N = in_sizes[0] / DIM;
  const int E = in_sizes[1] / 2;
  const int* src = ei;
  const int* dst = ei + E;

  char* w = (char*)d_ws;
  __half* h    = (__half*)w; w += (size_t)N*DIM*2;
  __half* Wt   = (__half*)w; w += (size_t)DIM*DIM*2;
  float* as_   = (float*)w; w += (size_t)N*HD*4;
  float* ad_   = (float*)w; w += (size_t)N*HD*4;
  int* csr_src = (int*)w;   w += (size_t)(E+16)*4;     // +16 pad for chunk over-read
  int* cnt_seg = (int*)w;   w += (size_t)SEG*N*4;      // per-segment histogram planes (6.4MB)
  int* cofs    = (int*)w;   w += (size_t)SEG*N*4;      // per-segment exclusive offsets (6.4MB)
  int* bsum    = (int*)w;   w += 256*4;
  int* row_ofs = (int*)w;   w += (size_t)(N+1)*4;

  const int chunk = (N + 255) / 256;        // 196 for N=50000 (must be <=256)
  const int RB    = (N + RSIZE-1) >> RSHIFT;// 7 ranges
  const int Eseg  = (E + SEG-1) / SEG;      // 18750 edges/segment
  const int gb    = (N + 63) / 64;          // 782 gemm blocks

  hipLaunchKernelGGL(k_wprep,   dim3(64),          dim3(256), 0, stream, W, Wt);
  hipLaunchKernelGGL(k_gemm,    dim3(gb),          dim3(256), 0, stream, x, Wt, a_src, a_dst, h, as_, ad_, N);
  hipLaunchKernelGGL(k_count,   dim3(RB*SEG),      dim3(256), 0, stream, dst, cnt_seg, E, N, Eseg);
  hipLaunchKernelGGL(k_scan1,   dim3(256),         dim3(256), 0, stream, cnt_seg, bsum, chunk, N);
  hipLaunchKernelGGL(k_scan2,   dim3(1),           dim3(256), 0, stream, bsum, row_ofs, N);
  hipLaunchKernelGGL(k_scan3,   dim3(256),         dim3(256), 0, stream, cnt_seg, bsum, row_ofs, cofs, chunk, N);
  hipLaunchKernelGGL(k_scatter, dim3(RB*SEG),      dim3(256), 0, stream, src, dst, cofs, csr_src, E, N, Eseg);
  hipLaunchKernelGGL(k_aggr,    dim3((N+3)/4),     dim3(256), 0, stream, h, as_, ad_, row_ofs, csr_src, bias, out, N);
}

// Round 23
// 116.972 us; speedup vs baseline: 1.1878x; 1.1878x over previous
//
#include <hip/hip_runtime.h>
#include <hip/hip_fp16.h>

#define HD 8
#define CD 16
#define DIM 128
#define NEG_SLOPE 0.2f
#define RSHIFT 13
#define RSIZE (1<<RSHIFT)                   // 8192-node range per histogram block (32KB LDS)
#define SEG 32                              // edge segments
#define SCAT_SHIFT 12                       // 4096-node ranges for scatter write locality

typedef __attribute__((ext_vector_type(8))) _Float16 f16x8;
typedef __attribute__((ext_vector_type(4))) float    f32x4;

static __device__ __forceinline__ float lrelu(float v){ return v > 0.f ? v : NEG_SLOPE*v; }

// ---------------- K0: W fp32 [k][c] -> Wt fp16 [c][k] ----------------
__global__ __launch_bounds__(256) void k_wprep(const float* __restrict__ W, __half* __restrict__ Wt){
  int idx = blockIdx.x*256 + threadIdx.x;
  if (idx < DIM*DIM){
    int k = idx >> 7, c = idx & 127;
    Wt[(size_t)c*DIM + k] = __float2half(W[idx]);
  }
}

// ---------------- K1: h = x @ W via MFMA fp16, + alpha epilogue (r10-verified) -------------
__global__ __launch_bounds__(256, 3) void k_gemm(const float* __restrict__ x,
    const __half* __restrict__ Wt, const float* __restrict__ a_src_g, const float* __restrict__ a_dst_g,
    __half* __restrict__ hout, float* __restrict__ as_o, float* __restrict__ ad_o, int N)
{
  __shared__ __half xs[64*136];
  const int tid  = threadIdx.x;
  const int lane = tid & 63;
  const int wv   = tid >> 6;
  const long nbase = (long)blockIdx.x * 64;

  #pragma unroll
  for (int it = 0; it < 8; ++it){
    int lin = it*1024 + tid*4;
    int row = lin >> 7, col = lin & 127;
    long node = nbase + row;
    float4 v = make_float4(0.f,0.f,0.f,0.f);
    if (node < N) v = *(const float4*)(x + node*DIM + col);
    __half2* dstp = (__half2*)(xs + row*136 + col);
    dstp[0] = __floats2half2_rn(v.x, v.y);
    dstp[1] = __floats2half2_rn(v.z, v.w);
  }
  __syncthreads();

  const int lrow = lane & 15;
  const int g    = lane >> 4;

  f16x8 af[4];
  #pragma unroll
  for (int ks = 0; ks < 4; ++ks)
    af[ks] = *(const f16x8*)(xs + (wv*16 + lrow)*136 + ks*32 + g*8);

  f32x4 accs[8];
  #pragma unroll
  for (int t = 0; t < 8; ++t){
    f32x4 acc = {0.f,0.f,0.f,0.f};
    #pragma unroll
    for (int ks = 0; ks < 4; ++ks){
      f16x8 bf = *(const f16x8*)(Wt + (size_t)(t*16 + lrow)*DIM + ks*32 + g*8);
      acc = __builtin_amdgcn_mfma_f32_16x16x32_f16(af[ks], bf, acc, 0, 0, 0);
    }
    accs[t] = acc;
  }

  #pragma unroll
  for (int t = 0; t < 8; ++t)
    #pragma unroll
    for (int i = 0; i < 4; ++i)
      xs[(wv*16 + g*4 + i)*136 + t*16 + lrow] = __float2half(accs[t][i]);
  __syncthreads();

  #pragma unroll
  for (int j = 0; j < 4; ++j){
    int idx = j*256 + tid;
    int row = idx >> 4, seg = idx & 15;
    long node = nbase + row;
    if (node < N){
      uint4 v = *(const uint4*)((const char*)xs + row*272 + seg*16);
      *(uint4*)(hout + node*DIM + seg*8) = v;
    }
  }
  #pragma unroll
  for (int j = 0; j < 2; ++j){
    int idx = j*256 + tid;
    int row = idx >> 3, hd = idx & 7;
    long node = nbase + row;
    if (node < N){
      const __half* hp = xs + row*136 + hd*16;
      float ps = 0.f, pd = 0.f;
      #pragma unroll
      for (int cc = 0; cc < 16; ++cc){
        float hv = __half2float(hp[cc]);
        ps += hv * a_src_g[hd*16 + cc];
        pd += hv * a_dst_g[hd*16 + cc];
      }
      as_o[node*HD + hd] = ps;
      ad_o[node*HD + hd] = pd;
    }
  }
}

// ---------------- K2: LDS-histogram count + slot recording (NO global atomics) -------------
// Block (range p, segment s): 32KB LDS hist; stream segment-s dsts (coalesced); in-range
// edges do an LDS atomicAdd whose RETURN VALUE is recorded as slot[e] (the allocator,
// captured for free). Histogram plane dumped coalescedly. Structure proven cheap in r22
// (k_count never surfaced); the slot store is sparse but fire-and-forget.
__global__ __launch_bounds__(256) void k_count(const int* __restrict__ dst,
                                               int* __restrict__ cnt_seg, int* __restrict__ slot,
                                               int E, int N, int Eseg){
  __shared__ int hist[RSIZE];
  const int p = blockIdx.x / SEG;
  const int s = blockIdx.x % SEG;
  for (int i = threadIdx.x; i < RSIZE; i += 256) hist[i] = 0;
  __syncthreads();
  const int lo = p << RSHIFT;
  const int end = min((s+1)*Eseg, E);
  for (int e = s*Eseg + threadIdx.x; e < end; e += 256){
    unsigned r = (unsigned)(dst[e] - lo);
    if (r < RSIZE)
      slot[e] = atomicAdd(&hist[r], 1);
  }
  __syncthreads();
  for (int i = threadIdx.x; i < RSIZE; i += 256){
    int node = lo + i;
    if (node < N) cnt_seg[(size_t)s*N + node] = hist[i];
  }
}

// ---------------- CSR scans over SEG planes ----------------
__global__ __launch_bounds__(256) void k_scan1(const int* __restrict__ cnt_seg, int* __restrict__ bsum,
                                               int chunk, int N){
  __shared__ int tmp[256];
  int t = threadIdx.x;
  int i = blockIdx.x*chunk + t;
  int v = 0;
  if (t < chunk && i < N){
    #pragma unroll
    for (int s = 0; s < SEG; ++s) v += cnt_seg[(size_t)s*N + i];
  }
  tmp[t] = v; __syncthreads();
  for (int off = 128; off > 0; off >>= 1){
    if (t < off) tmp[t] += tmp[t+off];
    __syncthreads();
  }
  if (t == 0) bsum[blockIdx.x] = tmp[0];
}

__global__ __launch_bounds__(256) void k_scan2(int* __restrict__ bsum, int* __restrict__ row_ofs, int N){
  __shared__ int tmp[256];
  int t = threadIdx.x;
  int v = bsum[t];
  tmp[t] = v; __syncthreads();
  for (int off = 1; off < 256; off <<= 1){
    int u = (t >= off) ? tmp[t-off] : 0;
    __syncthreads();
    tmp[t] += u;
    __syncthreads();
  }
  bsum[t] = tmp[t] - v;            // exclusive
  if (t == 255) row_ofs[N] = tmp[255];
}

// scan3: row_ofs + s-major per-segment offsets cofs[s*N+d]
__global__ __launch_bounds__(256) void k_scan3(const int* __restrict__ cnt_seg, const int* __restrict__ bsum,
                                               int* __restrict__ row_ofs, int* __restrict__ cofs,
                                               int chunk, int N){
  __shared__ int tmp[256];
  int t = threadIdx.x;
  int i = blockIdx.x*chunk + t;
  int v[SEG]; int tot = 0;
  if (t < chunk && i < N){
    #pragma unroll
    for (int s = 0; s < SEG; ++s){ v[s] = cnt_seg[(size_t)s*N + i]; tot += v[s]; }
  }
  tmp[t] = tot; __syncthreads();
  for (int off = 1; off < 256; off <<= 1){
    int u = (t >= off) ? tmp[t-off] : 0;
    __syncthreads();
    tmp[t] += u;
    __syncthreads();
  }
  int excl = tmp[t] - tot;
  int bbase = bsum[blockIdx.x];
  if (t < chunk && i < N){
    int run = bbase + excl;
    row_ofs[i] = run;
    #pragma unroll
    for (int s = 0; s < SEG; ++s){ cofs[(size_t)s*N + i] = run; run += v[s]; }
  }
}

// ---------------- K3: atomic-free full-grid scatter (r20-proven structure) ----------------
// pos = cofs[(e/Eseg)*N + dst] + slot[e]. 2344 blocks (r22 post-mortem: the (p,s) grid's
// 224 blocks = 7.7% occupancy killed it). Pass-partitioned writes (r16-proven locality).
__global__ void k_scatter(const int* __restrict__ src, const int* __restrict__ dst,
                          const int* __restrict__ slot, const int* __restrict__ cofs,
                          int* __restrict__ csr_src, int E, int N, int Eseg, int npass){
  int e = blockIdx.x*256 + threadIdx.x;
  if (e >= E) return;
  int d = dst[e];
  int s = src[e];
  int seg = e / Eseg;
  int pos = cofs[(size_t)seg*N + d] + slot[e];
  int myp = d >> SCAT_SHIFT;
  for (int p = 0; p < npass; ++p){
    if (myp == p)
      csr_src[pos] = s;
    asm volatile("" ::: "memory");
  }
}

// ---------------- K4: weighted gather (fp16 h), COOPERATIVE weights ----------------
__global__ __launch_bounds__(256) void k_aggr(const __half* __restrict__ h,
    const float* __restrict__ as_, const float* __restrict__ ad_,
    const int* __restrict__ row_ofs, const int* __restrict__ csr_src,
    const float* __restrict__ bias, float* __restrict__ out, int N)
{
  const int n = blockIdx.x*4 + (threadIdx.x >> 6);
  if (n >= N) return;
  const int t  = threadIdx.x & 63;
  const int hb = t >> 3;
  const int sl = t & 7;
  const int off = t*2;

  const float ad_n = ad_[(size_t)n*HD + hb];
  const float w_self = __expf(lrelu(as_[(size_t)n*HD + hb] + ad_n));

  float sum = w_self;
  float2 hv = __half22float2(*(const __half2*)(h + (size_t)n*DIM + off));
  float2 acc; acc.x = w_self*hv.x; acc.y = w_self*hv.y;

  const int ofs = row_ofs[n];
  const int deg = row_ofs[n+1] - ofs;

  for (int jb = 0; jb < deg; jb += 16){
    const int c = deg - jb;               // valid slots this chunk (>=1)
    int s[16];
    #pragma unroll
    for (int q = 0; q < 16; ++q){
      int sq = csr_src[ofs + jb + q];     // padded: safe to over-read
      s[q] = (q < c) ? sq : n;
    }

    __half2 hq[16];                        // 16 independent gathers, 1 VGPR each
    #pragma unroll
    for (int q = 0; q < 16; ++q)
      hq[q] = *(const __half2*)(h + (size_t)s[q]*DIM + off);

    float v0 = __expf(lrelu(as_[(size_t)s[sl]*HD + hb] + ad_n));
    float v1 = __expf(lrelu(as_[(size_t)s[sl+8]*HD + hb] + ad_n));
    const float wv0 = (sl     < c) ? v0 : 0.f;
    const float wv1 = (sl + 8 < c) ? v1 : 0.f;

    #pragma unroll
    for (int q = 0; q < 8; ++q){
      float w0 = __shfl(wv0, hb*8 + q);
      float2 hf = __half22float2(hq[q]);
      sum += w0; acc.x += w0*hf.x; acc.y += w0*hf.y;
    }
    #pragma unroll
    for (int q = 0; q < 8; ++q){
      float w1 = __shfl(wv1, hb*8 + q);
      float2 hf = __half22float2(hq[8+q]);
      sum += w1; acc.x += w1*hf.x; acc.y += w1*hf.y;
    }
  }

  const float2 bv = *(const float2*)(bias + off);
  const float inv = 1.0f / (sum + 1e-16f);
  float2 o;
  o.x = acc.x*inv + bv.x;
  o.y = acc.y*inv + bv.y;
  *(float2*)(out + (size_t)n*DIM + off) = o;
}

extern "C" void kernel_launch(void* const* d_in, const int* in_sizes, int n_in,
                              void* d_out, int out_size, void* d_ws, size_t ws_size,
                              hipStream_t stream)
{
  const float* x     = (const float*)d_in[0];
  const int*   ei    = (const int*)  d_in[1];
  const float* W     = (const float*)d_in[2];
  const float* a_src = (const float*)d_in[3];
  const float* a_dst = (const float*)d_in[4];
  const float* bias  = (const float*)d_in[5];
  float* out = (float*)d_out;

  const int N = in_sizes[0] / DIM;
  const int E = in_sizes[1] / 2;
  const int* src = ei;
  const int* dst = ei + E;

  char* w = (char*)d_ws;
  __half* h    = (__half*)w; w += (size_t)N*DIM*2;
  __half* Wt   = (__half*)w; w += (size_t)DIM*DIM*2;
  float* as_   = (float*)w; w += (size_t)N*HD*4;
  float* ad_   = (float*)w; w += (size_t)N*HD*4;
  int* csr_src = (int*)w;   w += (size_t)(E+16)*4;     // +16 pad for chunk over-read
  int* slot    = (int*)w;   w += (size_t)E*4;          // within-(seg,dst) local slot
  int* cnt_seg = (int*)w;   w += (size_t)SEG*N*4;      // per-segment histogram planes (6.4MB)
  int* cofs    = (int*)w;   w += (size_t)SEG*N*4;      // per-segment exclusive offsets (6.4MB)
  int* bsum    = (int*)w;   w += 256*4;
  int* row_ofs = (int*)w;   w += (size_t)(N+1)*4;

  const int chunk = (N + 255) / 256;        // 196 for N=50000 (must be <=256)
  const int RB    = (N + RSIZE-1) >> RSHIFT;// 7 ranges
  const int Eseg  = (E + SEG-1) / SEG;      // 18750 edges/segment
  const int gb    = (N + 63) / 64;          // 782 gemm blocks
  const int npass = (N >> SCAT_SHIFT) + 1;  // 13 passes

  hipLaunchKernelGGL(k_wprep,   dim3(64),          dim3(256), 0, stream, W, Wt);
  hipLaunchKernelGGL(k_gemm,    dim3(gb),          dim3(256), 0, stream, x, Wt, a_src, a_dst, h, as_, ad_, N);
  hipLaunchKernelGGL(k_count,   dim3(RB*SEG),      dim3(256), 0, stream, dst, cnt_seg, slot, E, N, Eseg);
  hipLaunchKernelGGL(k_scan1,   dim3(256),         dim3(256), 0, stream, cnt_seg, bsum, chunk, N);
  hipLaunchKernelGGL(k_scan2,   dim3(1),           dim3(256), 0, stream, bsum, row_ofs, N);
  hipLaunchKernelGGL(k_scan3,   dim3(256),         dim3(256), 0, stream, cnt_seg, bsum, row_ofs, cofs, chunk, N);
  hipLaunchKernelGGL(k_scatter, dim3((E+255)/256), dim3(256), 0, stream, src, dst, slot, cofs, csr_src, E, N, Eseg, npass);
  hipLaunchKernelGGL(k_aggr,    dim3((N+3)/4),     dim3(256), 0, stream, h, as_, ad_, row_ofs, csr_src, bias, out, N);
}

// Round 24
// 106.079 us; speedup vs baseline: 1.3097x; 1.1027x over previous
//
#include <hip/hip_runtime.h>
#include <hip/hip_fp16.h>

#define HD 8
#define CD 16
#define DIM 128
#define NEG_SLOPE 0.2f
#define RSHIFT 14
#define RSIZE (1<<RSHIFT)                   // 16384-node range, packed 16-bit -> 32KB LDS
#define SEG 32                              // edge segments
#define SCAT_SHIFT 12                       // 4096-node ranges for scatter write locality

typedef __attribute__((ext_vector_type(8))) _Float16 f16x8;
typedef __attribute__((ext_vector_type(4))) float    f32x4;

static __device__ __forceinline__ float lrelu(float v){ return v > 0.f ? v : NEG_SLOPE*v; }

// ---------------- K0: W fp32 [k][c] -> Wt fp16 [c][k] ----------------
__global__ __launch_bounds__(256) void k_wprep(const float* __restrict__ W, __half* __restrict__ Wt){
  int idx = blockIdx.x*256 + threadIdx.x;
  if (idx < DIM*DIM){
    int k = idx >> 7, c = idx & 127;
    Wt[(size_t)c*DIM + k] = __float2half(W[idx]);
  }
}

// ---------------- K1: fused MFMA-gemm + packed-LDS-histogram count -------------------------
// blocks [0,gb): h = x@W via MFMA fp16 + alpha epilogue (r10-verified layout).
// blocks [gb,..): count block (range p, segment s): 32KB LDS = 16384 PACKED 16-bit counters;
// atomicAdd(1<<((r&1)*16)) on the int pair; the return value's field IS slot[e] (free
// allocator). No global atomics (r18/r21: per-op fabric cost, scope/address-independent);
// fusion restores the r17-measured overlap (+12.5us); 128 count blocks ride behind 782
// gemm blocks so count-grid parallelism doesn't matter (r22/r23 lesson).
__global__ __launch_bounds__(256, 3) void k_gc(const float* __restrict__ x,
    const __half* __restrict__ Wt, const float* __restrict__ a_src_g, const float* __restrict__ a_dst_g,
    __half* __restrict__ hout, float* __restrict__ as_o, float* __restrict__ ad_o, int N,
    const int* __restrict__ dst, unsigned short* __restrict__ cnt_seg, int* __restrict__ slot,
    int E, int Eseg, int gb)
{
  __shared__ union { __half xs[64*136]; unsigned int hist[RSIZE/2]; } sm;   // 32KB
  const int b = blockIdx.x;

  if (b >= gb){                                // ---- count + slot part ----
    const int cb = b - gb;
    const int p = cb / SEG;
    const int s = cb % SEG;
    for (int i = threadIdx.x; i < RSIZE/2; i += 256) sm.hist[i] = 0;
    __syncthreads();
    const int lo = p << RSHIFT;
    const int end = min((s+1)*Eseg, E);
    for (int e = s*Eseg + threadIdx.x; e < end; e += 256){
      unsigned r = (unsigned)(dst[e] - lo);
      if (r < RSIZE){
        unsigned sh = (r & 1u) << 4;
        unsigned old = atomicAdd(&sm.hist[r >> 1], 1u << sh);
        slot[e] = (int)((old >> sh) & 0xffffu);
      }
    }
    __syncthreads();
    for (int i = threadIdx.x; i < RSIZE; i += 256){
      int node = lo + i;
      if (node < N)
        cnt_seg[(size_t)s*N + node] =
          (unsigned short)((sm.hist[i >> 1] >> ((i & 1u) << 4)) & 0xffffu);
    }
    return;
  }

  // ---- gemm part ----
  const int tid  = threadIdx.x;
  const int lane = tid & 63;
  const int wv   = tid >> 6;
  const long nbase = (long)b * 64;

  #pragma unroll
  for (int it = 0; it < 8; ++it){
    int lin = it*1024 + tid*4;
    int row = lin >> 7, col = lin & 127;
    long node = nbase + row;
    float4 v = make_float4(0.f,0.f,0.f,0.f);
    if (node < N) v = *(const float4*)(x + node*DIM + col);
    __half2* dstp = (__half2*)(sm.xs + row*136 + col);
    dstp[0] = __floats2half2_rn(v.x, v.y);
    dstp[1] = __floats2half2_rn(v.z, v.w);
  }
  __syncthreads();

  const int lrow = lane & 15;
  const int g    = lane >> 4;

  f16x8 af[4];
  #pragma unroll
  for (int ks = 0; ks < 4; ++ks)
    af[ks] = *(const f16x8*)(sm.xs + (wv*16 + lrow)*136 + ks*32 + g*8);

  f32x4 accs[8];
  #pragma unroll
  for (int t = 0; t < 8; ++t){
    f32x4 acc = {0.f,0.f,0.f,0.f};
    #pragma unroll
    for (int ks = 0; ks < 4; ++ks){
      f16x8 bf = *(const f16x8*)(Wt + (size_t)(t*16 + lrow)*DIM + ks*32 + g*8);
      acc = __builtin_amdgcn_mfma_f32_16x16x32_f16(af[ks], bf, acc, 0, 0, 0);
    }
    accs[t] = acc;
  }

  #pragma unroll
  for (int t = 0; t < 8; ++t)
    #pragma unroll
    for (int i = 0; i < 4; ++i)
      sm.xs[(wv*16 + g*4 + i)*136 + t*16 + lrow] = __float2half(accs[t][i]);
  __syncthreads();

  #pragma unroll
  for (int j = 0; j < 4; ++j){
    int idx = j*256 + tid;
    int row = idx >> 4, seg = idx & 15;
    long node = nbase + row;
    if (node < N){
      uint4 v = *(const uint4*)((const char*)sm.xs + row*272 + seg*16);
      *(uint4*)(hout + node*DIM + seg*8) = v;
    }
  }
  #pragma unroll
  for (int j = 0; j < 2; ++j){
    int idx = j*256 + tid;
    int row = idx >> 3, hd = idx & 7;
    long node = nbase + row;
    if (node < N){
      const __half* hp = sm.xs + row*136 + hd*16;
      float ps = 0.f, pd = 0.f;
      #pragma unroll
      for (int cc = 0; cc < 16; ++cc){
        float hv = __half2float(hp[cc]);
        ps += hv * a_src_g[hd*16 + cc];
        pd += hv * a_dst_g[hd*16 + cc];
      }
      as_o[node*HD + hd] = ps;
      ad_o[node*HD + hd] = pd;
    }
  }
}

// ---------------- CSR scans over SEG ushort planes ----------------
__global__ __launch_bounds__(256) void k_scan1(const unsigned short* __restrict__ cnt_seg,
                                               int* __restrict__ bsum, int chunk, int N){
  __shared__ int tmp[256];
  int t = threadIdx.x;
  int i = blockIdx.x*chunk + t;
  int v = 0;
  if (t < chunk && i < N){
    #pragma unroll
    for (int s = 0; s < SEG; ++s) v += cnt_seg[(size_t)s*N + i];
  }
  tmp[t] = v; __syncthreads();
  for (int off = 128; off > 0; off >>= 1){
    if (t < off) tmp[t] += tmp[t+off];
    __syncthreads();
  }
  if (t == 0) bsum[blockIdx.x] = tmp[0];
}

__global__ __launch_bounds__(256) void k_scan2(int* __restrict__ bsum, int* __restrict__ row_ofs, int N){
  __shared__ int tmp[256];
  int t = threadIdx.x;
  int v = bsum[t];
  tmp[t] = v; __syncthreads();
  for (int off = 1; off < 256; off <<= 1){
    int u = (t >= off) ? tmp[t-off] : 0;
    __syncthreads();
    tmp[t] += u;
    __syncthreads();
  }
  bsum[t] = tmp[t] - v;            // exclusive
  if (t == 255) row_ofs[N] = tmp[255];
}

// scan3: row_ofs + s-major per-segment offsets cofs[s*N+d]
__global__ __launch_bounds__(256) void k_scan3(const unsigned short* __restrict__ cnt_seg,
                                               const int* __restrict__ bsum,
                                               int* __restrict__ row_ofs, int* __restrict__ cofs,
                                               int chunk, int N){
  __shared__ int tmp[256];
  int t = threadIdx.x;
  int i = blockIdx.x*chunk + t;
  int v[SEG]; int tot = 0;
  if (t < chunk && i < N){
    #pragma unroll
    for (int s = 0; s < SEG; ++s){ v[s] = cnt_seg[(size_t)s*N + i]; tot += v[s]; }
  }
  tmp[t] = tot; __syncthreads();
  for (int off = 1; off < 256; off <<= 1){
    int u = (t >= off) ? tmp[t-off] : 0;
    __syncthreads();
    tmp[t] += u;
    __syncthreads();
  }
  int excl = tmp[t] - tot;
  int bbase = bsum[blockIdx.x];
  if (t < chunk && i < N){
    int run = bbase + excl;
    row_ofs[i] = run;
    #pragma unroll
    for (int s = 0; s < SEG; ++s){ cofs[(size_t)s*N + i] = run; run += v[s]; }
  }
}

// ---------------- atomic-free full-grid scatter (r20-proven structure) ----------------
// pos = cofs[(e/Eseg)*N + dst] + slot[e]; pass-partitioned writes (r16-proven locality).
__global__ void k_scatter(const int* __restrict__ src, const int* __restrict__ dst,
                          const int* __restrict__ slot, const int* __restrict__ cofs,
                          int* __restrict__ csr_src, int E, int N, int Eseg, int npass){
  int e = blockIdx.x*256 + threadIdx.x;
  if (e >= E) return;
  int d = dst[e];
  int s = src[e];
  int seg = e / Eseg;
  int pos = cofs[(size_t)seg*N + d] + slot[e];
  int myp = d >> SCAT_SHIFT;
  for (int p = 0; p < npass; ++p){
    if (myp == p)
      csr_src[pos] = s;
    asm volatile("" ::: "memory");
  }
}

// ---------------- K4: weighted gather (fp16 h), COOPERATIVE weights ----------------
__global__ __launch_bounds__(256) void k_aggr(const __half* __restrict__ h,
    const float* __restrict__ as_, const float* __restrict__ ad_,
    const int* __restrict__ row_ofs, const int* __restrict__ csr_src,
    const float* __restrict__ bias, float* __restrict__ out, int N)
{
  const int n = blockIdx.x*4 + (threadIdx.x >> 6);
  if (n >= N) return;
  const int t  = threadIdx.x & 63;
  const int hb = t >> 3;
  const int sl = t & 7;
  const int off = t*2;

  const float ad_n = ad_[(size_t)n*HD + hb];
  const float w_self = __expf(lrelu(as_[(size_t)n*HD + hb] + ad_n));

  float sum = w_self;
  float2 hv = __half22float2(*(const __half2*)(h + (size_t)n*DIM + off));
  float2 acc; acc.x = w_self*hv.x; acc.y = w_self*hv.y;

  const int ofs = row_ofs[n];
  const int deg = row_ofs[n+1] - ofs;

  for (int jb = 0; jb < deg; jb += 16){
    const int c = deg - jb;               // valid slots this chunk (>=1)
    int s[16];
    #pragma unroll
    for (int q = 0; q < 16; ++q){
      int sq = csr_src[ofs + jb + q];     // padded: safe to over-read
      s[q] = (q < c) ? sq : n;
    }

    __half2 hq[16];                        // 16 independent gathers, 1 VGPR each
    #pragma unroll
    for (int q = 0; q < 16; ++q)
      hq[q] = *(const __half2*)(h + (size_t)s[q]*DIM + off);

    float v0 = __expf(lrelu(as_[(size_t)s[sl]*HD + hb] + ad_n));
    float v1 = __expf(lrelu(as_[(size_t)s[sl+8]*HD + hb] + ad_n));
    const float wv0 = (sl     < c) ? v0 : 0.f;
    const float wv1 = (sl + 8 < c) ? v1 : 0.f;

    #pragma unroll
    for (int q = 0; q < 8; ++q){
      float w0 = __shfl(wv0, hb*8 + q);
      float2 hf = __half22float2(hq[q]);
      sum += w0; acc.x += w0*hf.x; acc.y += w0*hf.y;
    }
    #pragma unroll
    for (int q = 0; q < 8; ++q){
      float w1 = __shfl(wv1, hb*8 + q);
      float2 hf = __half22float2(hq[8+q]);
      sum += w1; acc.x += w1*hf.x; acc.y += w1*hf.y;
    }
  }

  const float2 bv = *(const float2*)(bias + off);
  const float inv = 1.0f / (sum + 1e-16f);
  float2 o;
  o.x = acc.x*inv + bv.x;
  o.y = acc.y*inv + bv.y;
  *(float2*)(out + (size_t)n*DIM + off) = o;
}

extern "C" void kernel_launch(void* const* d_in, const int* in_sizes, int n_in,
                              void* d_out, int out_size, void* d_ws, size_t ws_size,
                              hipStream_t stream)
{
  const float* x     = (const float*)d_in[0];
  const int*   ei    = (const int*)  d_in[1];
  const float* W     = (const float*)d_in[2];
  const float* a_src = (const float*)d_in[3];
  const float* a_dst = (const float*)d_in[4];
  const float* bias  = (const float*)d_in[5];
  float* out = (float*)d_out;

  const int N = in_sizes[0] / DIM;
  const int E = in_sizes[1] / 2;
  const int* src = ei;
  const int* dst = ei + E;

  char* w = (char*)d_ws;
  __half* h    = (__half*)w; w += (size_t)N*DIM*2;
  __half* Wt   = (__half*)w; w += (size_t)DIM*DIM*2;
  float* as_   = (float*)w; w += (size_t)N*HD*4;
  float* ad_   = (float*)w; w += (size_t)N*HD*4;
  int* csr_src = (int*)w;   w += (size_t)(E+16)*4;           // +16 pad for chunk over-read
  int* slot    = (int*)w;   w += (size_t)E*4;                // within-(seg,dst) local slot
  unsigned short* cnt_seg = (unsigned short*)w; w += (size_t)SEG*N*2;  // ushort planes (3.2MB)
  int* cofs    = (int*)w;   w += (size_t)SEG*N*4;            // per-segment offsets (6.4MB)
  int* bsum    = (int*)w;   w += 256*4;
  int* row_ofs = (int*)w;   w += (size_t)(N+1)*4;

  const int chunk = (N + 255) / 256;        // 196 for N=50000 (must be <=256)
  const int RB    = (N + RSIZE-1) >> RSHIFT;// 4 ranges
  const int Eseg  = (E + SEG-1) / SEG;      // 18750 edges/segment
  const int gb    = (N + 63) / 64;          // 782 gemm blocks
  const int npass = (N >> SCAT_SHIFT) + 1;  // 13 passes

  hipLaunchKernelGGL(k_wprep,   dim3(64),          dim3(256), 0, stream, W, Wt);
  hipLaunchKernelGGL(k_gc,      dim3(gb + RB*SEG), dim3(256), 0, stream,
                     x, Wt, a_src, a_dst, h, as_, ad_, N, dst, cnt_seg, slot, E, Eseg, gb);
  hipLaunchKernelGGL(k_scan1,   dim3(256),         dim3(256), 0, stream, cnt_seg, bsum, chunk, N);
  hipLaunchKernelGGL(k_scan2,   dim3(1),           dim3(256), 0, stream, bsum, row_ofs, N);
  hipLaunchKernelGGL(k_scan3,   dim3(256),         dim3(256), 0, stream, cnt_seg, bsum, row_ofs, cofs, chunk, N);
  hipLaunchKernelGGL(k_scatter, dim3((E+255)/256), dim3(256), 0, stream, src, dst, slot, cofs, csr_src, E, N, Eseg, npass);
  hipLaunchKernelGGL(k_aggr,    dim3((N+3)/4),     dim3(256), 0, stream, h, as_, ad_, row_ofs, csr_src, bias, out, N);
}

// Round 25
// 94.864 us; speedup vs baseline: 1.4646x; 1.1182x over previous
//
#include <hip/hip_runtime.h>
#include <hip/hip_fp16.h>

#define HD 8
#define CD 16
#define DIM 128
#define NEG_SLOPE 0.2f
#define SCAT_SHIFT 12                       // 4096-node ranges -> ~213KB csr slice per pass

typedef __attribute__((ext_vector_type(8))) _Float16 f16x8;
typedef __attribute__((ext_vector_type(4))) float    f32x4;

static __device__ __forceinline__ float lrelu(float v){ return v > 0.f ? v : NEG_SLOPE*v; }

// ---------------- K1: fused W-prep + cnt-zero (r20-verified) ----------------
__global__ __launch_bounds__(256) void k_prep(const float* __restrict__ W, __half* __restrict__ Wt,
                                              int* __restrict__ cnt, int N){
  int b = blockIdx.x;
  if (b < 64){
    int idx = b*256 + threadIdx.x;           // 16384 elements of W
    int k = idx >> 7, c = idx & 127;
    Wt[(size_t)c*DIM + k] = __float2half(W[idx]);
  } else {
    int i = (b-64)*256 + threadIdx.x;
    if (i < N) cnt[i] = 0;
  }
}

// ---------------- K2: fused MFMA-gemm + slot-recording global-atomic count -----------------
// r20-verified champion. r18/r21/r24 all failed to beat the plain global atomic
// (replication null, scope null, LDS histogram slower w/ 1M bank conflicts) — the
// ~200ns/op fabric cost is structural; the slot (atomic return value) makes the
// scatter atomic-free, which IS the win (96.7->r20).
__global__ __launch_bounds__(256, 3) void k_gc(const float* __restrict__ x,
    const __half* __restrict__ Wt, const float* __restrict__ a_src_g, const float* __restrict__ a_dst_g,
    __half* __restrict__ hout, float* __restrict__ as_o, float* __restrict__ ad_o, int N,
    const int* __restrict__ dst, int* __restrict__ cnt, int* __restrict__ slot, int E, int gb)
{
  __shared__ __half xs[64*136];                // pad 128->136: breaks LDS bank aliasing
  const int b = blockIdx.x;

  if (b >= gb){                                // ---- count + slot part ----
    int e = (b-gb)*256 + threadIdx.x;
    if (e < E) slot[e] = atomicAdd(&cnt[dst[e]], 1);
    return;
  }

  // ---- gemm part (r10-verified MFMA layout) ----
  const int tid  = threadIdx.x;
  const int lane = tid & 63;
  const int wv   = tid >> 6;
  const long nbase = (long)b * 64;

  #pragma unroll
  for (int it = 0; it < 8; ++it){
    int lin = it*1024 + tid*4;
    int row = lin >> 7, col = lin & 127;
    long node = nbase + row;
    float4 v = make_float4(0.f,0.f,0.f,0.f);
    if (node < N) v = *(const float4*)(x + node*DIM + col);
    __half2* dstp = (__half2*)(xs + row*136 + col);
    dstp[0] = __floats2half2_rn(v.x, v.y);
    dstp[1] = __floats2half2_rn(v.z, v.w);
  }
  __syncthreads();

  const int lrow = lane & 15;
  const int g    = lane >> 4;

  f16x8 af[4];
  #pragma unroll
  for (int ks = 0; ks < 4; ++ks)
    af[ks] = *(const f16x8*)(xs + (wv*16 + lrow)*136 + ks*32 + g*8);

  f32x4 accs[8];
  #pragma unroll
  for (int t = 0; t < 8; ++t){
    f32x4 acc = {0.f,0.f,0.f,0.f};
    #pragma unroll
    for (int ks = 0; ks < 4; ++ks){
      f16x8 bf = *(const f16x8*)(Wt + (size_t)(t*16 + lrow)*DIM + ks*32 + g*8);
      acc = __builtin_amdgcn_mfma_f32_16x16x32_f16(af[ks], bf, acc, 0, 0, 0);
    }
    accs[t] = acc;
  }

  #pragma unroll
  for (int t = 0; t < 8; ++t)
    #pragma unroll
    for (int i = 0; i < 4; ++i)
      xs[(wv*16 + g*4 + i)*136 + t*16 + lrow] = __float2half(accs[t][i]);
  __syncthreads();

  #pragma unroll
  for (int j = 0; j < 4; ++j){
    int idx = j*256 + tid;
    int row = idx >> 4, seg = idx & 15;
    long node = nbase + row;
    if (node < N){
      uint4 v = *(const uint4*)((const char*)xs + row*272 + seg*16);
      *(uint4*)(hout + node*DIM + seg*8) = v;
    }
  }
  #pragma unroll
  for (int j = 0; j < 2; ++j){
    int idx = j*256 + tid;
    int row = idx >> 3, hd = idx & 7;
    long node = nbase + row;
    if (node < N){
      const __half* hp = xs + row*136 + hd*16;
      float ps = 0.f, pd = 0.f;
      #pragma unroll
      for (int cc = 0; cc < 16; ++cc){
        float hv = __half2float(hp[cc]);
        ps += hv * a_src_g[hd*16 + cc];
        pd += hv * a_dst_g[hd*16 + cc];
      }
      as_o[node*HD + hd] = ps;
      ad_o[node*HD + hd] = pd;
    }
  }
}

// ---------------- CSR scan, 2 kernels (scan2 folded into scan3) ----------------
__global__ __launch_bounds__(256) void k_scan1(const int* __restrict__ cnt, int* __restrict__ bsum,
                                               int chunk, int N){
  __shared__ int tmp[256];
  int t = threadIdx.x;
  int i = blockIdx.x*chunk + t;
  int v = (t < chunk && i < N) ? cnt[i] : 0;
  tmp[t] = v; __syncthreads();
  for (int off = 128; off > 0; off >>= 1){
    if (t < off) tmp[t] += tmp[t+off];
    __syncthreads();
  }
  if (t == 0) bsum[blockIdx.x] = tmp[0];
}

// scan23: every block redundantly prefix-scans the 256 bsum entries in LDS (cheap,
// fully parallel) -> no separate scan2 launch. Then scans its own chunk of cnt.
__global__ __launch_bounds__(256) void k_scan23(const int* __restrict__ cnt, const int* __restrict__ bsum,
                                                int* __restrict__ row_ofs, int chunk, int N){
  __shared__ int bs[256];
  __shared__ int tmp[256];
  int t = threadIdx.x;

  int bv = bsum[t];
  bs[t] = bv; __syncthreads();
  for (int off = 1; off < 256; off <<= 1){
    int u = (t >= off) ? bs[t-off] : 0;
    __syncthreads();
    bs[t] += u;
    __syncthreads();
  }
  // bs = inclusive scan of bsum. Exclusive base for this block:
  const int bbase = bs[blockIdx.x] - bsum[blockIdx.x];
  if (blockIdx.x == 0 && t == 0) row_ofs[N] = bs[255];   // total edge count

  int i = blockIdx.x*chunk + t;
  int v = (t < chunk && i < N) ? cnt[i] : 0;
  tmp[t] = v; __syncthreads();
  for (int off = 1; off < 256; off <<= 1){
    int u = (t >= off) ? tmp[t-off] : 0;
    __syncthreads();
    tmp[t] += u;
    __syncthreads();
  }
  int excl = tmp[t] - v;
  if (t < chunk && i < N)
    row_ofs[i] = bbase + excl;
}

// ---------------- atomic-free pass-partitioned scatter (r20-verified) ----------------
__global__ void k_scatter(const int* __restrict__ src, const int* __restrict__ dst,
                          const int* __restrict__ slot, const int* __restrict__ row_ofs,
                          int* __restrict__ csr_src, int E, int npass){
  int e = blockIdx.x*256 + threadIdx.x;
  if (e >= E) return;
  int d = dst[e];
  int s = src[e];
  int pos = row_ofs[d] + slot[e];          // row_ofs: 200KB, L2-resident random read
  int myp = d >> SCAT_SHIFT;
  for (int p = 0; p < npass; ++p){
    if (myp == p)
      csr_src[pos] = s;
    asm volatile("" ::: "memory");
  }
}

// ---------------- K4: weighted gather (fp16 h), COOPERATIVE weights (r20-verified) ---------
__global__ __launch_bounds__(256) void k_aggr(const __half* __restrict__ h,
    const float* __restrict__ as_, const float* __restrict__ ad_,
    const int* __restrict__ row_ofs, const int* __restrict__ csr_src,
    const float* __restrict__ bias, float* __restrict__ out, int N)
{
  const int n = blockIdx.x*4 + (threadIdx.x >> 6);
  if (n >= N) return;
  const int t  = threadIdx.x & 63;
  const int hb = t >> 3;
  const int sl = t & 7;
  const int off = t*2;

  const float ad_n = ad_[(size_t)n*HD + hb];
  const float w_self = __expf(lrelu(as_[(size_t)n*HD + hb] + ad_n));

  float sum = w_self;
  float2 hv = __half22float2(*(const __half2*)(h + (size_t)n*DIM + off));
  float2 acc; acc.x = w_self*hv.x; acc.y = w_self*hv.y;

  const int ofs = row_ofs[n];
  const int deg = row_ofs[n+1] - ofs;

  for (int jb = 0; jb < deg; jb += 16){
    const int c = deg - jb;               // valid slots this chunk (>=1)
    int s[16];
    #pragma unroll
    for (int q = 0; q < 16; ++q){
      int sq = csr_src[ofs + jb + q];     // padded: safe to over-read
      s[q] = (q < c) ? sq : n;
    }

    __half2 hq[16];                        // 16 independent gathers, 1 VGPR each
    #pragma unroll
    for (int q = 0; q < 16; ++q)
      hq[q] = *(const __half2*)(h + (size_t)s[q]*DIM + off);

    float v0 = __expf(lrelu(as_[(size_t)s[sl]*HD + hb] + ad_n));
    float v1 = __expf(lrelu(as_[(size_t)s[sl+8]*HD + hb] + ad_n));
    const float wv0 = (sl     < c) ? v0 : 0.f;
    const float wv1 = (sl + 8 < c) ? v1 : 0.f;

    #pragma unroll
    for (int q = 0; q < 8; ++q){
      float w0 = __shfl(wv0, hb*8 + q);
      float2 hf = __half22float2(hq[q]);
      sum += w0; acc.x += w0*hf.x; acc.y += w0*hf.y;
    }
    #pragma unroll
    for (int q = 0; q < 8; ++q){
      float w1 = __shfl(wv1, hb*8 + q);
      float2 hf = __half22float2(hq[8+q]);
      sum += w1; acc.x += w1*hf.x; acc.y += w1*hf.y;
    }
  }

  const float2 bv = *(const float2*)(bias + off);
  const float inv = 1.0f / (sum + 1e-16f);
  float2 o;
  o.x = acc.x*inv + bv.x;
  o.y = acc.y*inv + bv.y;
  *(float2*)(out + (size_t)n*DIM + off) = o;
}

extern "C" void kernel_launch(void* const* d_in, const int* in_sizes, int n_in,
                              void* d_out, int out_size, void* d_ws, size_t ws_size,
                              hipStream_t stream)
{
  const float* x     = (const float*)d_in[0];
  const int*   ei    = (const int*)  d_in[1];
  const float* W     = (const float*)d_in[2];
  const float* a_src = (const float*)d_in[3];
  const float* a_dst = (const float*)d_in[4];
  const float* bias  = (const float*)d_in[5];
  float* out = (float*)d_out;

  const int N = in_sizes[0] / DIM;
  const int E = in_sizes[1] / 2;
  const int* src = ei;
  const int* dst = ei + E;

  char* w = (char*)d_ws;
  __half* h    = (__half*)w; w += (size_t)N*DIM*2;
  __half* Wt   = (__half*)w; w += (size_t)DIM*DIM*2;
  float* as_   = (float*)w; w += (size_t)N*HD*4;
  float* ad_   = (float*)w; w += (size_t)N*HD*4;
  int* csr_src = (int*)w;   w += (size_t)(E+16)*4;     // +16 pad for chunk over-read
  int* slot    = (int*)w;   w += (size_t)E*4;          // within-dst slot per edge
  int* cnt     = (int*)w;   w += (size_t)N*4;
  int* bsum    = (int*)w;   w += 256*4;
  int* row_ofs = (int*)w;   w += (size_t)(N+1)*4;

  const int chunk = (N + 255) / 256;        // 196 for N=50000 (must be <=256)
  const int npass = (N >> SCAT_SHIFT) + 1;  // 13 for N=50000
  const int gb    = (N + 63) / 64;          // 782 gemm blocks
  const int cb    = (E + 255) / 256;        // 2344 count blocks

  hipLaunchKernelGGL(k_prep,    dim3(64 + (N+255)/256), dim3(256), 0, stream, W, Wt, cnt, N);
  hipLaunchKernelGGL(k_gc,      dim3(gb + cb),          dim3(256), 0, stream,
                     x, Wt, a_src, a_dst, h, as_, ad_, N, dst, cnt, slot, E, gb);
  hipLaunchKernelGGL(k_scan1,   dim3(256),              dim3(256), 0, stream, cnt, bsum, chunk, N);
  hipLaunchKernelGGL(k_scan23,  dim3(256),              dim3(256), 0, stream, cnt, bsum, row_ofs, chunk, N);
  hipLaunchKernelGGL(k_scatter, dim3((E+255)/256),      dim3(256), 0, stream, src, dst, slot, row_ofs, csr_src, E, npass);
  hipLaunchKernelGGL(k_aggr,    dim3((N+3)/4),          dim3(256), 0, stream, h, as_, ad_, row_ofs, csr_src, bias, out, N);
}